// Round 5
// baseline (576.326 us; speedup 1.0000x reference)
//
#include <hip/hip_runtime.h>

#define IMG_B 256
#define IMG_H 224
#define IMG_W 224
#define HWPIX 50176

// exact IEEE f32 ops, no contraction, matching numpy's elementwise semantics
#define FA(a,b) __fadd_rn((a),(b))
#define FM(a,b) __fmul_rn((a),(b))
#define FS(a,b) __fsub_rn((a),(b))
#define FD(a,b) __fdiv_rn((a),(b))

// python-float scalars cast to f32 exactly as numpy weak-scalar promotion does
__device__ __forceinline__ float VBF()   { return (float)(9.0/30.0*(1.9-0.1)+0.1); }
__device__ __forceinline__ float OMVBF() { return (float)(1.0 - (9.0/30.0*(1.9-0.1)+0.1)); }
__device__ __forceinline__ float VSF()   { return (float)(9.0/30.0*1.0); }

// y = x*s + m for cols j-1..j+4 of one row; OOB (pad) -> 0.0f (pad applies to y)
__device__ __forceinline__ void load_y6(const float* __restrict__ rp, int j, bool valid,
                                        float s, float m, float* y6) {
    if (!valid) {
#pragma unroll
        for (int t = 0; t < 6; ++t) y6[t] = 0.0f;
        return;
    }
    const float4 v = *(const float4*)(rp + j);
    y6[0] = (j > 0) ? FA(FM(rp[j - 1], s), m) : 0.0f;
    y6[1] = FA(FM(v.x, s), m);
    y6[2] = FA(FM(v.y, s), m);
    y6[3] = FA(FM(v.z, s), m);
    y6[4] = FA(FM(v.w, s), m);
    y6[5] = (j + 4 < IMG_W) ? FA(FM(rp[j + 4], s), m) : 0.0f;
}

// y1 = vb*y + (1-vb)*blur for 4 consecutive pixels (b,c,i,j..j+3).
// blur = left-fold of 9 terms in (ki,kj) raster order, f32, zero-pad terms included.
__device__ __forceinline__ void y1_quad(const float* __restrict__ x, float s, float m,
                                        int b, int c, int i, int j, float* y1o) {
    const float WN = 1.0f / 13.0f, WC = 5.0f / 13.0f;
    const float* rp = x + (size_t)(b * 3 + c) * HWPIX + (size_t)i * IMG_W;
    float yU[6], yC[6], yD[6];
    load_y6(rp - IMG_W, j, i > 0,         s, m, yU);
    load_y6(rp,         j, true,          s, m, yC);
    load_y6(rp + IMG_W, j, i < IMG_H - 1, s, m, yD);
#pragma unroll
    for (int mm = 0; mm < 4; ++mm) {
        float acc = 0.0f;
        acc = FA(acc, FM(WN, yU[mm + 0]));
        acc = FA(acc, FM(WN, yU[mm + 1]));
        acc = FA(acc, FM(WN, yU[mm + 2]));
        acc = FA(acc, FM(WN, yC[mm + 0]));
        acc = FA(acc, FM(WC, yC[mm + 1]));
        acc = FA(acc, FM(WN, yC[mm + 2]));
        acc = FA(acc, FM(WN, yD[mm + 0]));
        acc = FA(acc, FM(WN, yD[mm + 1]));
        acc = FA(acc, FM(WN, yD[mm + 2]));
        y1o[mm] = FA(FM(yC[mm + 1], VBF()), FM(acc, OMVBF()));
    }
}

// ---- Kernel A1: per half-image, numpy-pairwise partial sum of gray(y1) ----
// numpy pairwise over n=50176: perfect binary tree over 512 ordered leaves,
// leaf sizes cycle [96,96,96,104] (from n2 -= n2%8 at n=392).
// Block (b, half) = 256 threads = 256 leaves -> subtree root (n=25088 node).
__global__ __launch_bounds__(256) void kA1(const float* __restrict__ x,
                                           const float* __restrict__ mean_,
                                           const float* __restrict__ std_,
                                           float* __restrict__ part) {
    const int half = blockIdx.x & 1, b = blockIdx.x >> 1;
    const int t = threadIdx.x;
    const int l = half * 256 + t;                 // global leaf index 0..511
    const int p0 = 392 * (l >> 2) + 96 * (l & 3); // leaf start (raster)
    const int nq = ((l & 3) == 3) ? 26 : 24;      // quads (96 or 104 px)
    const float s0 = std_[0], s1 = std_[1], s2 = std_[2];
    const float m0 = mean_[0], m1 = mean_[1], m2 = mean_[2];
    const float C0 = 0.299f, C1 = 0.587f, C2 = 0.114f;

    float r[8];
    for (int q = 0; q < nq; ++q) {
        const int p = p0 + q * 4;
        const int i = p / IMG_W, j = p % IMG_W;   // j%4==0, quad never crosses rows
        float a[4], bb[4], cc[4];
        y1_quad(x, s0, m0, b, 0, i, j, a);
        y1_quad(x, s1, m1, b, 1, i, j, bb);
        y1_quad(x, s2, m2, b, 2, i, j, cc);
        const int e0 = (q & 1) * 4;
#pragma unroll
        for (int mm = 0; mm < 4; ++mm) {
            const float g = FA(FA(FM(C0, a[mm]), FM(C1, bb[mm])), FM(C2, cc[mm]));
            if (q < 2) r[e0 + mm] = g;                      // r[e] = a[e]
            else       r[e0 + mm] = FA(r[e0 + mm], g);      // r[e] += a[8k+e]
        }
    }
    float res = FA(FA(FA(r[0], r[1]), FA(r[2], r[3])),
                   FA(FA(r[4], r[5]), FA(r[6], r[7])));

    // exact binary combine of 256 ordered leaf sums (ping-pong regions, no alias)
    __shared__ float T[511];
    T[t] = res;
    __syncthreads();
    int src = 0, dst = 256, n = 128;
    while (n >= 1) {
        if (t < n) T[dst + t] = FA(T[src + 2 * t], T[src + 2 * t + 1]);
        __syncthreads();
        src = dst; dst += n; n >>= 1;
    }
    if (t == 0) part[blockIdx.x] = T[src];
}

// ---- Kernel A2: gm[b] = (left25088 + right25088) / 50176  (f32 ops) ----
__global__ __launch_bounds__(256) void kA2(const float* __restrict__ part,
                                           float* __restrict__ gm) {
    const int t = threadIdx.x;
    gm[t] = FD(FA(part[2 * t], part[2 * t + 1]), 50176.0f);
}

// ---- Kernel B: main fused pass, exact f32 chain ----
__global__ __launch_bounds__(256) void kB(const float* __restrict__ x,
                                          const float* __restrict__ mean_,
                                          const float* __restrict__ std_,
                                          const float* __restrict__ gm,
                                          float* __restrict__ out) {
    const int q = blockIdx.x * 256 + threadIdx.x;
    const int j = (q % (IMG_W / 4)) * 4;
    int r = q / (IMG_W / 4);
    const int i = r % IMG_H; r /= IMG_H;
    const int c = r % 3;
    const int b = r / 3;

    const float s = std_[c], m = mean_[c];
    float y1[4];
    y1_quad(x, s, m, b, c, i, j, y1);
    const float g = gm[b];

    float ov[4];
#pragma unroll
    for (int mm = 0; mm < 4; ++mm) {
        const float y2 = FA(FM(y1[mm], VBF()), FM(g, OMVBF()));
        const float y3 = FM(y2, VBF());
        const float y4 = (y3 < VSF()) ? y3 : FS(1.0f, y3);
        ov[mm] = FD(FS(y4, m), s);
    }
    float4 o;
    o.x = ov[0]; o.y = ov[1]; o.z = ov[2]; o.w = ov[3];
    *(float4*)(out + (size_t)(b * 3 + c) * HWPIX + (size_t)i * IMG_W + j) = o;
}

extern "C" void kernel_launch(void* const* d_in, const int* in_sizes, int n_in,
                              void* d_out, int out_size, void* d_ws, size_t ws_size,
                              hipStream_t stream) {
    const float* x     = (const float*)d_in[0];
    const float* mean_ = (const float*)d_in[1];
    const float* std_  = (const float*)d_in[2];
    float* out = (float*)d_out;

    float* part = (float*)d_ws;        // 512 f32
    float* gm   = part + 512;          // 256 f32

    kA1<<<IMG_B * 2, 256, 0, stream>>>(x, mean_, std_, part);
    kA2<<<1, 256, 0, stream>>>(part, gm);

    const int quads = IMG_B * 3 * IMG_H * (IMG_W / 4);
    kB<<<quads / 256, 256, 0, stream>>>(x, mean_, std_, gm, out);
}

// Round 6
// 257.513 us; speedup vs baseline: 2.2380x; 2.2380x over previous
//
#include <hip/hip_runtime.h>

#define IMG_B 256
#define IMG_H 224
#define IMG_W 224
#define HWPIX 50176

// exact IEEE f32 ops, no contraction, matching numpy's elementwise semantics
#define FA(a,b) __fadd_rn((a),(b))
#define FM(a,b) __fmul_rn((a),(b))
#define FS(a,b) __fsub_rn((a),(b))
#define FD(a,b) __fdiv_rn((a),(b))

// python-float scalars cast to f32 exactly as numpy weak-scalar promotion does
__device__ __forceinline__ float VBF()   { return (float)(9.0/30.0*(1.9-0.1)+0.1); }
__device__ __forceinline__ float OMVBF() { return (float)(1.0 - (9.0/30.0*(1.9-0.1)+0.1)); }
__device__ __forceinline__ float VSF()   { return (float)(9.0/30.0*1.0); }

// y = x*s + m for cols j-1..j+4 of one row; OOB (pad) -> 0.0f (pad applies to y)
__device__ __forceinline__ void load_y6(const float* __restrict__ rp, int j, bool valid,
                                        float s, float m, float* y6) {
    if (!valid) {
#pragma unroll
        for (int t = 0; t < 6; ++t) y6[t] = 0.0f;
        return;
    }
    const float4 v = *(const float4*)(rp + j);
    y6[0] = (j > 0) ? FA(FM(rp[j - 1], s), m) : 0.0f;
    y6[1] = FA(FM(v.x, s), m);
    y6[2] = FA(FM(v.y, s), m);
    y6[3] = FA(FM(v.z, s), m);
    y6[4] = FA(FM(v.w, s), m);
    y6[5] = (j + 4 < IMG_W) ? FA(FM(rp[j + 4], s), m) : 0.0f;
}

// y1 = vb*y + (1-vb)*blur for 4 consecutive pixels (b,c,i,j..j+3).
// blur = left-fold of 9 terms in (ki,kj) raster order, f32, zero-pad terms included.
__device__ __forceinline__ void y1_quad(const float* __restrict__ x, float s, float m,
                                        int b, int c, int i, int j, float* y1o) {
    const float WN = 1.0f / 13.0f, WC = 5.0f / 13.0f;
    const float* rp = x + (size_t)(b * 3 + c) * HWPIX + (size_t)i * IMG_W;
    float yU[6], yC[6], yD[6];
    load_y6(rp - IMG_W, j, i > 0,         s, m, yU);
    load_y6(rp,         j, true,          s, m, yC);
    load_y6(rp + IMG_W, j, i < IMG_H - 1, s, m, yD);
#pragma unroll
    for (int mm = 0; mm < 4; ++mm) {
        float acc = 0.0f;
        acc = FA(acc, FM(WN, yU[mm + 0]));
        acc = FA(acc, FM(WN, yU[mm + 1]));
        acc = FA(acc, FM(WN, yU[mm + 2]));
        acc = FA(acc, FM(WN, yC[mm + 0]));
        acc = FA(acc, FM(WC, yC[mm + 1]));
        acc = FA(acc, FM(WN, yC[mm + 2]));
        acc = FA(acc, FM(WN, yD[mm + 0]));
        acc = FA(acc, FM(WN, yD[mm + 1]));
        acc = FA(acc, FM(WN, yD[mm + 2]));
        y1o[mm] = FA(FM(yC[mm + 1], VBF()), FM(acc, OMVBF()));
    }
}

// ---- Kernel A1 (coalesced rewrite): per half-image numpy-pairwise sum of gray(y1) ----
// numpy pairwise over n=50176: perfect binary tree over 512 ordered leaves,
// leaf sizes cycling [96,96,96,104] (groups of 392 px). Half-image = 256 leaves
// = 8 chunks x 3136 px (8 leaf-groups = 32 leaves = 14 whole rows per chunk).
// Phase 1: gray(y1) computed coalesced (quad/thread) into LDS.
// Phase 2: 8 threads/leaf walk the 8 interleaved chains (exact base case), then
//          exact chain-combine and exact 256-leaf binary tree.
__global__ __launch_bounds__(256) void kA1(const float* __restrict__ x,
                                           const float* __restrict__ mean_,
                                           const float* __restrict__ std_,
                                           float* __restrict__ part) {
    const int half = blockIdx.x & 1, b = blockIdx.x >> 1;
    const int t = threadIdx.x;
    const float s0 = std_[0], s1 = std_[1], s2 = std_[2];
    const float m0 = mean_[0], m1 = mean_[1], m2 = mean_[2];
    const float C0 = 0.299f, C1 = 0.587f, C2 = 0.114f;

    __shared__ float G[3136];   // chunk gray values (raster order)
    __shared__ float CH[256];   // 8 chain partials x 32 leaves
    __shared__ float LS[256];   // 256 ordered leaf sums
    __shared__ float T[511];    // binary combine tree

    const int halfbase = half * 25088;

    for (int ck = 0; ck < 8; ++ck) {
        const int chunkpix = halfbase + ck * 3136;

        // ---- phase 1: coalesced gray(y1) into LDS ----
        for (int qi = t; qi < 784; qi += 256) {
            const int p = chunkpix + qi * 4;
            const int i = p / IMG_W, j = p % IMG_W;   // quads never cross rows
            float a[4], bb[4], cc[4];
            y1_quad(x, s0, m0, b, 0, i, j, a);
            y1_quad(x, s1, m1, b, 1, i, j, bb);
            y1_quad(x, s2, m2, b, 2, i, j, cc);
#pragma unroll
            for (int mm = 0; mm < 4; ++mm)
                G[qi * 4 + mm] = FA(FA(FM(C0, a[mm]), FM(C1, bb[mm])), FM(C2, cc[mm]));
        }
        __syncthreads();

        // ---- phase 2a: 8 chains per leaf, 32 leaves (exact numpy base case) ----
        {
            const int leaf = t >> 3, e = t & 7;                   // leaf 0..31, chain 0..7
            const int ls = 392 * (leaf >> 2) + 96 * (leaf & 3);   // local leaf start
            const int nk = ((leaf & 3) == 3) ? 13 : 12;           // size/8
            float r = G[ls + e];
            for (int k = 1; k < nk; ++k) r = FA(r, G[ls + 8 * k + e]);
            CH[leaf * 8 + e] = r;
        }
        __syncthreads();

        // ---- phase 2b: exact chain combine -> leaf sums ----
        if (t < 32) {
            const float* c8 = &CH[t * 8];
            LS[ck * 32 + t] = FA(FA(FA(c8[0], c8[1]), FA(c8[2], c8[3])),
                                 FA(FA(c8[4], c8[5]), FA(c8[6], c8[7])));
        }
        __syncthreads();   // protects G & CH reuse next chunk
    }

    // ---- exact binary combine of 256 ordered leaf sums ----
    T[t] = LS[t];
    __syncthreads();
    int src = 0, dst = 256, n = 128;
    while (n >= 1) {
        if (t < n) T[dst + t] = FA(T[src + 2 * t], T[src + 2 * t + 1]);
        __syncthreads();
        src = dst; dst += n; n >>= 1;
    }
    if (t == 0) part[blockIdx.x] = T[src];
}

// ---- Kernel A2: gm[b] = (left25088 + right25088) / 50176  (f32 ops) ----
__global__ __launch_bounds__(256) void kA2(const float* __restrict__ part,
                                           float* __restrict__ gm) {
    const int t = threadIdx.x;
    gm[t] = FD(FA(part[2 * t], part[2 * t + 1]), 50176.0f);
}

// ---- Kernel B: main fused pass, exact f32 chain ----
__global__ __launch_bounds__(256) void kB(const float* __restrict__ x,
                                          const float* __restrict__ mean_,
                                          const float* __restrict__ std_,
                                          const float* __restrict__ gm,
                                          float* __restrict__ out) {
    const int q = blockIdx.x * 256 + threadIdx.x;
    const int j = (q % (IMG_W / 4)) * 4;
    int r = q / (IMG_W / 4);
    const int i = r % IMG_H; r /= IMG_H;
    const int c = r % 3;
    const int b = r / 3;

    const float s = std_[c], m = mean_[c];
    float y1[4];
    y1_quad(x, s, m, b, c, i, j, y1);
    const float g = gm[b];

    float ov[4];
#pragma unroll
    for (int mm = 0; mm < 4; ++mm) {
        const float y2 = FA(FM(y1[mm], VBF()), FM(g, OMVBF()));
        const float y3 = FM(y2, VBF());
        const float y4 = (y3 < VSF()) ? y3 : FS(1.0f, y3);
        ov[mm] = FD(FS(y4, m), s);
    }
    float4 o;
    o.x = ov[0]; o.y = ov[1]; o.z = ov[2]; o.w = ov[3];
    *(float4*)(out + (size_t)(b * 3 + c) * HWPIX + (size_t)i * IMG_W + j) = o;
}

extern "C" void kernel_launch(void* const* d_in, const int* in_sizes, int n_in,
                              void* d_out, int out_size, void* d_ws, size_t ws_size,
                              hipStream_t stream) {
    const float* x     = (const float*)d_in[0];
    const float* mean_ = (const float*)d_in[1];
    const float* std_  = (const float*)d_in[2];
    float* out = (float*)d_out;

    float* part = (float*)d_ws;        // 512 f32
    float* gm   = part + 512;          // 256 f32

    kA1<<<IMG_B * 2, 256, 0, stream>>>(x, mean_, std_, part);
    kA2<<<1, 256, 0, stream>>>(part, gm);

    const int quads = IMG_B * 3 * IMG_H * (IMG_W / 4);
    kB<<<quads / 256, 256, 0, stream>>>(x, mean_, std_, gm, out);
}

// Round 7
// 177.046 us; speedup vs baseline: 3.2552x; 1.4545x over previous
//
#include <hip/hip_runtime.h>

#define IMG_B 256
#define IMG_H 224
#define IMG_W 224
#define HWPIX 50176

// exact IEEE f32 ops, no contraction, matching numpy's elementwise semantics
#define FA(a,b) __fadd_rn((a),(b))
#define FM(a,b) __fmul_rn((a),(b))
#define FS(a,b) __fsub_rn((a),(b))
#define FD(a,b) __fdiv_rn((a),(b))

// python-float scalars cast to f32 exactly as numpy weak-scalar promotion does
__device__ __forceinline__ float VBF()   { return (float)(9.0/30.0*(1.9-0.1)+0.1); }
__device__ __forceinline__ float OMVBF() { return (float)(1.0 - (9.0/30.0*(1.9-0.1)+0.1)); }
__device__ __forceinline__ float VSF()   { return (float)(9.0/30.0*1.0); }

// y = x*s + m for cols j-1..j+4 of one row; OOB (pad) -> 0.0f (pad applies to y)
__device__ __forceinline__ void load_y6(const float* __restrict__ rp, int j, bool valid,
                                        float s, float m, float* y6) {
    if (!valid) {
#pragma unroll
        for (int t = 0; t < 6; ++t) y6[t] = 0.0f;
        return;
    }
    const float4 v = *(const float4*)(rp + j);
    y6[0] = (j > 0) ? FA(FM(rp[j - 1], s), m) : 0.0f;
    y6[1] = FA(FM(v.x, s), m);
    y6[2] = FA(FM(v.y, s), m);
    y6[3] = FA(FM(v.z, s), m);
    y6[4] = FA(FM(v.w, s), m);
    y6[5] = (j + 4 < IMG_W) ? FA(FM(rp[j + 4], s), m) : 0.0f;
}

// y1 = vb*y + (1-vb)*blur for 4 consecutive pixels (b,c,i,j..j+3).
// blur = left-fold of 9 terms in (ki,kj) raster order, f32, zero-pad terms included.
__device__ __forceinline__ void y1_quad(const float* __restrict__ x, float s, float m,
                                        int b, int c, int i, int j, float* y1o) {
    const float WN = 1.0f / 13.0f, WC = 5.0f / 13.0f;
    const float* rp = x + (size_t)(b * 3 + c) * HWPIX + (size_t)i * IMG_W;
    float yU[6], yC[6], yD[6];
    load_y6(rp - IMG_W, j, i > 0,         s, m, yU);
    load_y6(rp,         j, true,          s, m, yC);
    load_y6(rp + IMG_W, j, i < IMG_H - 1, s, m, yD);
#pragma unroll
    for (int mm = 0; mm < 4; ++mm) {
        float acc = 0.0f;
        acc = FA(acc, FM(WN, yU[mm + 0]));
        acc = FA(acc, FM(WN, yU[mm + 1]));
        acc = FA(acc, FM(WN, yU[mm + 2]));
        acc = FA(acc, FM(WN, yC[mm + 0]));
        acc = FA(acc, FM(WC, yC[mm + 1]));
        acc = FA(acc, FM(WN, yC[mm + 2]));
        acc = FA(acc, FM(WN, yD[mm + 0]));
        acc = FA(acc, FM(WN, yD[mm + 1]));
        acc = FA(acc, FM(WN, yD[mm + 2]));
        y1o[mm] = FA(FM(yC[mm + 1], VBF()), FM(acc, OMVBF()));
    }
}

// ---- Kernel A1: one block = one 3136-px chunk = 32 aligned leaves of the
// numpy pairwise tree (512 leaves/image, sizes cycling [96,96,96,104]).
// Phase 1: gray(y1) coalesced (quad/thread) into LDS.
// Phase 2a: 8 chains/leaf x 32 leaves (exact numpy base case).
// Phase 2b: exact chain-combine -> 32 leaf sums -> exact 5-level subtree root.
// part[b*16+ck] = subtree root.  Grid: 256*16 = 4096 blocks.
__global__ __launch_bounds__(256) void kA1(const float* __restrict__ x,
                                           const float* __restrict__ mean_,
                                           const float* __restrict__ std_,
                                           float* __restrict__ part) {
    const int ck = blockIdx.x & 15, b = blockIdx.x >> 4;
    const int t = threadIdx.x;
    const float s0 = std_[0], s1 = std_[1], s2 = std_[2];
    const float m0 = mean_[0], m1 = mean_[1], m2 = mean_[2];
    const float C0 = 0.299f, C1 = 0.587f, C2 = 0.114f;

    __shared__ float G[3136];   // chunk gray values (raster order)
    __shared__ float CH[256];   // 8 chain partials x 32 leaves
    __shared__ float LS[32];    // 32 ordered leaf sums

    const int chunkpix = ck * 3136;

    // ---- phase 1: coalesced gray(y1) into LDS ----
    for (int qi = t; qi < 784; qi += 256) {
        const int p = chunkpix + qi * 4;
        const int i = p / IMG_W, j = p % IMG_W;   // quads never cross rows
        float a[4], bb[4], cc[4];
        y1_quad(x, s0, m0, b, 0, i, j, a);
        y1_quad(x, s1, m1, b, 1, i, j, bb);
        y1_quad(x, s2, m2, b, 2, i, j, cc);
#pragma unroll
        for (int mm = 0; mm < 4; ++mm)
            G[qi * 4 + mm] = FA(FA(FM(C0, a[mm]), FM(C1, bb[mm])), FM(C2, cc[mm]));
    }
    __syncthreads();

    // ---- phase 2a: 8 chains per leaf, 32 leaves (exact numpy base case) ----
    {
        const int leaf = t >> 3, e = t & 7;                   // leaf 0..31, chain 0..7
        const int ls = 392 * (leaf >> 2) + 96 * (leaf & 3);   // local leaf start
        const int nk = ((leaf & 3) == 3) ? 13 : 12;           // size/8
        float r = G[ls + e];
        for (int k = 1; k < nk; ++k) r = FA(r, G[ls + 8 * k + e]);
        CH[leaf * 8 + e] = r;
    }
    __syncthreads();

    // ---- phase 2b: exact chain combine -> leaf sums ----
    if (t < 32) {
        const float* c8 = &CH[t * 8];
        LS[t] = FA(FA(FA(c8[0], c8[1]), FA(c8[2], c8[3])),
                   FA(FA(c8[4], c8[5]), FA(c8[6], c8[7])));
    }
    __syncthreads();

    // ---- exact 5-level binary combine of 32 ordered leaf sums (thread 0) ----
    if (t == 0) {
        float v[32];
#pragma unroll
        for (int k = 0; k < 32; ++k) v[k] = LS[k];
        for (int n = 16; n >= 1; n >>= 1)
            for (int k = 0; k < n; ++k) v[k] = FA(v[2 * k], v[2 * k + 1]);
        part[blockIdx.x] = v[0];
    }
}

// ---- Kernel A2: gm[b] = exact 4-level fold of 16 chunk roots / 50176 ----
__global__ __launch_bounds__(256) void kA2(const float* __restrict__ part,
                                           float* __restrict__ gm) {
    const int b = threadIdx.x;
    float v[16];
#pragma unroll
    for (int k = 0; k < 16; ++k) v[k] = part[b * 16 + k];
#pragma unroll
    for (int n = 8; n >= 1; n >>= 1)
#pragma unroll
        for (int k = 0; k < 8; ++k)
            if (k < n) v[k] = FA(v[2 * k], v[2 * k + 1]);
    gm[b] = FD(v[0], 50176.0f);
}

// ---- Kernel B: main fused pass, exact f32 chain ----
__global__ __launch_bounds__(256) void kB(const float* __restrict__ x,
                                          const float* __restrict__ mean_,
                                          const float* __restrict__ std_,
                                          const float* __restrict__ gm,
                                          float* __restrict__ out) {
    const int q = blockIdx.x * 256 + threadIdx.x;
    const int j = (q % (IMG_W / 4)) * 4;
    int r = q / (IMG_W / 4);
    const int i = r % IMG_H; r /= IMG_H;
    const int c = r % 3;
    const int b = r / 3;

    const float s = std_[c], m = mean_[c];
    float y1[4];
    y1_quad(x, s, m, b, c, i, j, y1);
    const float g = gm[b];

    float ov[4];
#pragma unroll
    for (int mm = 0; mm < 4; ++mm) {
        const float y2 = FA(FM(y1[mm], VBF()), FM(g, OMVBF()));
        const float y3 = FM(y2, VBF());
        const float y4 = (y3 < VSF()) ? y3 : FS(1.0f, y3);
        ov[mm] = FD(FS(y4, m), s);
    }
    float4 o;
    o.x = ov[0]; o.y = ov[1]; o.z = ov[2]; o.w = ov[3];
    *(float4*)(out + (size_t)(b * 3 + c) * HWPIX + (size_t)i * IMG_W + j) = o;
}

extern "C" void kernel_launch(void* const* d_in, const int* in_sizes, int n_in,
                              void* d_out, int out_size, void* d_ws, size_t ws_size,
                              hipStream_t stream) {
    const float* x     = (const float*)d_in[0];
    const float* mean_ = (const float*)d_in[1];
    const float* std_  = (const float*)d_in[2];
    float* out = (float*)d_out;

    float* part = (float*)d_ws;        // 4096 f32 (16 chunk roots x 256 images)
    float* gm   = part + 4096;         // 256 f32

    kA1<<<IMG_B * 16, 256, 0, stream>>>(x, mean_, std_, part);
    kA2<<<1, 256, 0, stream>>>(part, gm);

    const int quads = IMG_B * 3 * IMG_H * (IMG_W / 4);
    kB<<<quads / 256, 256, 0, stream>>>(x, mean_, std_, gm, out);
}

// Round 8
// 152.485 us; speedup vs baseline: 3.7796x; 1.1611x over previous
//
#include <hip/hip_runtime.h>

#define IMG_B 256
#define IMG_H 224
#define IMG_W 224
#define HWPIX 50176

// exact IEEE f32 ops, no contraction, matching numpy's elementwise semantics
#define FA(a,b) __fadd_rn((a),(b))
#define FM(a,b) __fmul_rn((a),(b))
#define FS(a,b) __fsub_rn((a),(b))
#define FD(a,b) __fdiv_rn((a),(b))

// python-float scalars cast to f32 exactly as numpy weak-scalar promotion does
__device__ __forceinline__ float VBF()   { return (float)(9.0/30.0*(1.9-0.1)+0.1); }
__device__ __forceinline__ float OMVBF() { return (float)(1.0 - (9.0/30.0*(1.9-0.1)+0.1)); }
__device__ __forceinline__ float VSF()   { return (float)(9.0/30.0*1.0); }

// 6 y-taps (cols j-1..j+4) from an LDS row; col pad -> 0.0f (row pad rows are pre-zeroed)
__device__ __forceinline__ void lds_y6(const float* __restrict__ r, int j, float* y6) {
    const float4 v = *(const float4*)(r + j);
    y6[0] = (j > 0) ? r[j - 1] : 0.0f;
    y6[1] = v.x; y6[2] = v.y; y6[3] = v.z; y6[4] = v.w;
    y6[5] = (j + 4 < IMG_W) ? r[j + 4] : 0.0f;
}

// global-memory version (used by kB): y = x*s + m, OOB -> 0.0f
__device__ __forceinline__ void load_y6(const float* __restrict__ rp, int j, bool valid,
                                        float s, float m, float* y6) {
    if (!valid) {
#pragma unroll
        for (int t = 0; t < 6; ++t) y6[t] = 0.0f;
        return;
    }
    const float4 v = *(const float4*)(rp + j);
    y6[0] = (j > 0) ? FA(FM(rp[j - 1], s), m) : 0.0f;
    y6[1] = FA(FM(v.x, s), m);
    y6[2] = FA(FM(v.y, s), m);
    y6[3] = FA(FM(v.z, s), m);
    y6[4] = FA(FM(v.w, s), m);
    y6[5] = (j + 4 < IMG_W) ? FA(FM(rp[j + 4], s), m) : 0.0f;
}

// exact blur fold (9 terms, raster order) + y1 blend, for 4 pixels
__device__ __forceinline__ void y1_from_rows(const float* yU, const float* yC,
                                             const float* yD, float* y1o) {
    const float WN = 1.0f / 13.0f, WC = 5.0f / 13.0f;
#pragma unroll
    for (int mm = 0; mm < 4; ++mm) {
        float acc = 0.0f;
        acc = FA(acc, FM(WN, yU[mm + 0]));
        acc = FA(acc, FM(WN, yU[mm + 1]));
        acc = FA(acc, FM(WN, yU[mm + 2]));
        acc = FA(acc, FM(WN, yC[mm + 0]));
        acc = FA(acc, FM(WC, yC[mm + 1]));
        acc = FA(acc, FM(WN, yC[mm + 2]));
        acc = FA(acc, FM(WN, yD[mm + 0]));
        acc = FA(acc, FM(WN, yD[mm + 1]));
        acc = FA(acc, FM(WN, yD[mm + 2]));
        y1o[mm] = FA(FM(yC[mm + 1], VBF()), FM(acc, OMVBF()));
    }
}

// ---- Kernel A1: one block = one 3136-px chunk (14 rows) = 32 aligned leaves of
// the numpy pairwise tree. Per channel: stage 16 rows of y into LDS (coalesced,
// pad rows zeroed), compute y1 from LDS, accumulate gray in exact numpy order.
// Then exact chains/leaf-sums/subtree root as before. part[b*16+ck] = root.
__global__ __launch_bounds__(256) void kA1(const float* __restrict__ x,
                                           const float* __restrict__ mean_,
                                           const float* __restrict__ std_,
                                           float* __restrict__ part) {
    const int ck = blockIdx.x & 15, b = blockIdx.x >> 4;
    const int t = threadIdx.x;
    const int r0 = ck * 14;

    __shared__ float Y[16 * IMG_W];   // one channel's 16 staged y-rows
    __shared__ float G[3136];         // gray(y1) accumulator (raster order)
    __shared__ float CH[256];         // 8 chain partials x 32 leaves
    __shared__ float LS[32];          // 32 ordered leaf sums

    const float CGRAY[3] = {0.299f, 0.587f, 0.114f};

    for (int c = 0; c < 3; ++c) {
        const float s = std_[c], m = mean_[c];
        const float* xc = x + (size_t)(b * 3 + c) * HWPIX;

        // ---- stage: rows r0-1 .. r0+14 of y, coalesced float4, pad rows -> 0 ----
        for (int idx = t; idx < 896; idx += 256) {
            const int row = idx / 56, c4 = (idx % 56) * 4;
            const int gi = r0 - 1 + row;
            float4 v;
            if (gi >= 0 && gi < IMG_H) {
                const float4 xv = *(const float4*)(xc + (size_t)gi * IMG_W + c4);
                v.x = FA(FM(xv.x, s), m);
                v.y = FA(FM(xv.y, s), m);
                v.z = FA(FM(xv.z, s), m);
                v.w = FA(FM(xv.w, s), m);
            } else {
                v.x = v.y = v.z = v.w = 0.0f;
            }
            *(float4*)(&Y[row * IMG_W + c4]) = v;
        }
        __syncthreads();

        // ---- compute y1 from LDS, accumulate gray (exact association) ----
        for (int qi = t; qi < 784; qi += 256) {
            const int pl = qi * 4;
            const int lr = pl / IMG_W + 1, j = pl % IMG_W;
            float yU[6], yC[6], yD[6], y1[4];
            lds_y6(&Y[(lr - 1) * IMG_W], j, yU);
            lds_y6(&Y[lr * IMG_W],       j, yC);
            lds_y6(&Y[(lr + 1) * IMG_W], j, yD);
            y1_from_rows(yU, yC, yD, y1);
#pragma unroll
            for (int mm = 0; mm < 4; ++mm) {
                const float gc = FM(CGRAY[c], y1[mm]);
                G[pl + mm] = (c == 0) ? gc : FA(G[pl + mm], gc);
            }
        }
        __syncthreads();   // protects Y restage & G read-modify-write ordering
    }

    // ---- phase 2a: 8 chains per leaf, 32 leaves (exact numpy base case) ----
    {
        const int leaf = t >> 3, e = t & 7;
        const int ls = 392 * (leaf >> 2) + 96 * (leaf & 3);
        const int nk = ((leaf & 3) == 3) ? 13 : 12;
        float r = G[ls + e];
        for (int k = 1; k < nk; ++k) r = FA(r, G[ls + 8 * k + e]);
        CH[leaf * 8 + e] = r;
    }
    __syncthreads();

    // ---- phase 2b: exact chain combine -> leaf sums ----
    if (t < 32) {
        const float* c8 = &CH[t * 8];
        LS[t] = FA(FA(FA(c8[0], c8[1]), FA(c8[2], c8[3])),
                   FA(FA(c8[4], c8[5]), FA(c8[6], c8[7])));
    }
    __syncthreads();

    // ---- exact 5-level binary combine of 32 ordered leaf sums ----
    if (t == 0) {
        float v[32];
#pragma unroll
        for (int k = 0; k < 32; ++k) v[k] = LS[k];
        for (int n = 16; n >= 1; n >>= 1)
            for (int k = 0; k < n; ++k) v[k] = FA(v[2 * k], v[2 * k + 1]);
        part[blockIdx.x] = v[0];
    }
}

// ---- Kernel B: main fused pass; gm computed inline (one image per block) ----
__global__ __launch_bounds__(256) void kB(const float* __restrict__ x,
                                          const float* __restrict__ mean_,
                                          const float* __restrict__ std_,
                                          const float* __restrict__ part,
                                          float* __restrict__ out) {
    __shared__ float gsh;
    const int q = blockIdx.x * 256 + threadIdx.x;
    const int j = (q % (IMG_W / 4)) * 4;
    int r = q / (IMG_W / 4);
    const int i = r % IMG_H; r /= IMG_H;
    const int c = r % 3;
    const int b = r / 3;

    if (threadIdx.x == 0) {
        // exact 4-level fold of the 16 chunk roots, / 50176 (same as old kA2)
        const int bb = blockIdx.x / 147;   // 147 blocks per image
        float v[16];
#pragma unroll
        for (int k = 0; k < 16; ++k) v[k] = part[bb * 16 + k];
#pragma unroll
        for (int n = 8; n >= 1; n >>= 1)
#pragma unroll
            for (int k = 0; k < 8; ++k)
                if (k < n) v[k] = FA(v[2 * k], v[2 * k + 1]);
        gsh = FD(v[0], 50176.0f);
    }
    __syncthreads();
    const float g = gsh;

    const float s = std_[c], m = mean_[c];
    const float* rp = x + (size_t)(b * 3 + c) * HWPIX + (size_t)i * IMG_W;
    float yU[6], yC[6], yD[6], y1[4];
    load_y6(rp - IMG_W, j, i > 0,         s, m, yU);
    load_y6(rp,         j, true,          s, m, yC);
    load_y6(rp + IMG_W, j, i < IMG_H - 1, s, m, yD);
    y1_from_rows(yU, yC, yD, y1);

    float ov[4];
#pragma unroll
    for (int mm = 0; mm < 4; ++mm) {
        const float y2 = FA(FM(y1[mm], VBF()), FM(g, OMVBF()));
        const float y3 = FM(y2, VBF());
        const float y4 = (y3 < VSF()) ? y3 : FS(1.0f, y3);
        ov[mm] = FD(FS(y4, m), s);
    }
    float4 o;
    o.x = ov[0]; o.y = ov[1]; o.z = ov[2]; o.w = ov[3];
    *(float4*)(out + (size_t)(b * 3 + c) * HWPIX + (size_t)i * IMG_W + j) = o;
}

extern "C" void kernel_launch(void* const* d_in, const int* in_sizes, int n_in,
                              void* d_out, int out_size, void* d_ws, size_t ws_size,
                              hipStream_t stream) {
    const float* x     = (const float*)d_in[0];
    const float* mean_ = (const float*)d_in[1];
    const float* std_  = (const float*)d_in[2];
    float* out = (float*)d_out;

    float* part = (float*)d_ws;   // 4096 f32 (16 chunk roots x 256 images)

    kA1<<<IMG_B * 16, 256, 0, stream>>>(x, mean_, std_, part);

    const int quads = IMG_B * 3 * IMG_H * (IMG_W / 4);
    kB<<<quads / 256, 256, 0, stream>>>(x, mean_, std_, part, out);
}

// Round 9
// 119.376 us; speedup vs baseline: 4.8278x; 1.2773x over previous
//
#include <hip/hip_runtime.h>

#define IMG_B 256
#define IMG_H 224
#define IMG_W 224
#define HWPIX 50176

// exact IEEE f32 ops, no contraction, matching numpy's elementwise semantics
#define FA(a,b) __fadd_rn((a),(b))
#define FM(a,b) __fmul_rn((a),(b))
#define FS(a,b) __fsub_rn((a),(b))
#define FD(a,b) __fdiv_rn((a),(b))

// python-float scalars cast to f32 exactly as numpy weak-scalar promotion does
__device__ __forceinline__ float VBF()   { return (float)(9.0/30.0*(1.9-0.1)+0.1); }
__device__ __forceinline__ float OMVBF() { return (float)(1.0 - (9.0/30.0*(1.9-0.1)+0.1)); }
__device__ __forceinline__ float VSF()   { return (float)(9.0/30.0*1.0); }

// 6 y-taps (cols j-1..j+4) from an LDS row; col pad -> 0.0f (pad rows pre-zeroed)
__device__ __forceinline__ void lds_y6(const float* __restrict__ r, int j, float* y6) {
    const float4 v = *(const float4*)(r + j);
    y6[0] = (j > 0) ? r[j - 1] : 0.0f;
    y6[1] = v.x; y6[2] = v.y; y6[3] = v.z; y6[4] = v.w;
    y6[5] = (j + 4 < IMG_W) ? r[j + 4] : 0.0f;
}

// exact blur fold (9 terms, raster order) + y1 blend, for 4 pixels
__device__ __forceinline__ void y1_from_rows(const float* yU, const float* yC,
                                             const float* yD, float* y1o) {
    const float WN = 1.0f / 13.0f, WC = 5.0f / 13.0f;
#pragma unroll
    for (int mm = 0; mm < 4; ++mm) {
        float acc = 0.0f;
        acc = FA(acc, FM(WN, yU[mm + 0]));
        acc = FA(acc, FM(WN, yU[mm + 1]));
        acc = FA(acc, FM(WN, yU[mm + 2]));
        acc = FA(acc, FM(WN, yC[mm + 0]));
        acc = FA(acc, FM(WC, yC[mm + 1]));
        acc = FA(acc, FM(WN, yC[mm + 2]));
        acc = FA(acc, FM(WN, yD[mm + 0]));
        acc = FA(acc, FM(WN, yD[mm + 1]));
        acc = FA(acc, FM(WN, yD[mm + 2]));
        y1o[mm] = FA(FM(yC[mm + 1], VBF()), FM(acc, OMVBF()));
    }
}

// stage rows r0-1 .. r0+14 of y = s*x+m into LDS (coalesced float4, pad rows -> 0)
__device__ __forceinline__ void stage16(const float* __restrict__ xc, int r0,
                                        float s, float m, int t, float* __restrict__ Y) {
    for (int idx = t; idx < 896; idx += 256) {
        const int row = idx / 56, c4 = (idx % 56) * 4;
        const int gi = r0 - 1 + row;
        float4 v;
        if (gi >= 0 && gi < IMG_H) {
            const float4 xv = *(const float4*)(xc + (size_t)gi * IMG_W + c4);
            v.x = FA(FM(xv.x, s), m);
            v.y = FA(FM(xv.y, s), m);
            v.z = FA(FM(xv.z, s), m);
            v.w = FA(FM(xv.w, s), m);
        } else {
            v.x = v.y = v.z = v.w = 0.0f;
        }
        *(float4*)(&Y[row * IMG_W + c4]) = v;
    }
}

// ---- Kernel A1: one block = one 3136-px chunk (14 rows) = 32 aligned leaves of
// the numpy pairwise tree. Per channel: stage, blur from LDS, accumulate gray.
// Then exact chains / leaf sums / 5-level subtree root. part[b*16+ck] = root.
__global__ __launch_bounds__(256) void kA1(const float* __restrict__ x,
                                           const float* __restrict__ mean_,
                                           const float* __restrict__ std_,
                                           float* __restrict__ part) {
    const int ck = blockIdx.x & 15, b = blockIdx.x >> 4;
    const int t = threadIdx.x;
    const int r0 = ck * 14;

    __shared__ float Y[16 * IMG_W];
    __shared__ float G[3136];
    __shared__ float CH[256];
    __shared__ float LS[32];

    const float CGRAY[3] = {0.299f, 0.587f, 0.114f};

    for (int c = 0; c < 3; ++c) {
        const float s = std_[c], m = mean_[c];
        stage16(x + (size_t)(b * 3 + c) * HWPIX, r0, s, m, t, Y);
        __syncthreads();

        for (int qi = t; qi < 784; qi += 256) {
            const int pl = qi * 4;
            const int lr = qi / 56 + 1, j = (qi % 56) * 4;
            float yU[6], yC[6], yD[6], y1[4];
            lds_y6(&Y[(lr - 1) * IMG_W], j, yU);
            lds_y6(&Y[lr * IMG_W],       j, yC);
            lds_y6(&Y[(lr + 1) * IMG_W], j, yD);
            y1_from_rows(yU, yC, yD, y1);
#pragma unroll
            for (int mm = 0; mm < 4; ++mm) {
                const float gc = FM(CGRAY[c], y1[mm]);
                G[pl + mm] = (c == 0) ? gc : FA(G[pl + mm], gc);
            }
        }
        __syncthreads();
    }

    // ---- 8 chains per leaf, 32 leaves (exact numpy base case) ----
    {
        const int leaf = t >> 3, e = t & 7;
        const int ls = 392 * (leaf >> 2) + 96 * (leaf & 3);
        const int nk = ((leaf & 3) == 3) ? 13 : 12;
        float r = G[ls + e];
        for (int k = 1; k < nk; ++k) r = FA(r, G[ls + 8 * k + e]);
        CH[leaf * 8 + e] = r;
    }
    __syncthreads();

    if (t < 32) {
        const float* c8 = &CH[t * 8];
        LS[t] = FA(FA(FA(c8[0], c8[1]), FA(c8[2], c8[3])),
                   FA(FA(c8[4], c8[5]), FA(c8[6], c8[7])));
    }
    __syncthreads();

    if (t == 0) {
        float v[32];
#pragma unroll
        for (int k = 0; k < 32; ++k) v[k] = LS[k];
        for (int n = 16; n >= 1; n >>= 1)
            for (int k = 0; k < n; ++k) v[k] = FA(v[2 * k], v[2 * k + 1]);
        part[blockIdx.x] = v[0];
    }
}

// ---- Kernel B: one block = one 14-row chunk of one (b,c); staged like kA1 ----
// grid (16, 3, 256): ck = x, c = y, b = z  (no div/mod for b,c)
__global__ __launch_bounds__(256) void kB(const float* __restrict__ x,
                                          const float* __restrict__ mean_,
                                          const float* __restrict__ std_,
                                          const float* __restrict__ part,
                                          float* __restrict__ out) {
    const int ck = blockIdx.x, c = blockIdx.y, b = blockIdx.z;
    const int t = threadIdx.x;
    const int r0 = ck * 14;

    __shared__ float Y[16 * IMG_W];
    __shared__ float gsh;

    const float s = std_[c], m = mean_[c];
    stage16(x + (size_t)(b * 3 + c) * HWPIX, r0, s, m, t, Y);

    if (t == 0) {
        // exact 4-level fold of the 16 chunk roots, / 50176
        float v[16];
#pragma unroll
        for (int k = 0; k < 16; ++k) v[k] = part[b * 16 + k];
#pragma unroll
        for (int n = 8; n >= 1; n >>= 1)
#pragma unroll
            for (int k = 0; k < 8; ++k)
                if (k < n) v[k] = FA(v[2 * k], v[2 * k + 1]);
        gsh = FD(v[0], 50176.0f);
    }
    __syncthreads();
    const float g = gsh;

    float* oc = out + (size_t)(b * 3 + c) * HWPIX + (size_t)r0 * IMG_W;

    for (int qi = t; qi < 784; qi += 256) {
        const int lr = qi / 56 + 1, j = (qi % 56) * 4;
        float yU[6], yC[6], yD[6], y1[4];
        lds_y6(&Y[(lr - 1) * IMG_W], j, yU);
        lds_y6(&Y[lr * IMG_W],       j, yC);
        lds_y6(&Y[(lr + 1) * IMG_W], j, yD);
        y1_from_rows(yU, yC, yD, y1);

        float ov[4];
#pragma unroll
        for (int mm = 0; mm < 4; ++mm) {
            const float y2 = FA(FM(y1[mm], VBF()), FM(g, OMVBF()));
            const float y3 = FM(y2, VBF());
            const float y4 = (y3 < VSF()) ? y3 : FS(1.0f, y3);
            ov[mm] = FD(FS(y4, m), s);
        }
        float4 o;
        o.x = ov[0]; o.y = ov[1]; o.z = ov[2]; o.w = ov[3];
        *(float4*)(oc + (size_t)(lr - 1) * IMG_W + j) = o;
    }
}

extern "C" void kernel_launch(void* const* d_in, const int* in_sizes, int n_in,
                              void* d_out, int out_size, void* d_ws, size_t ws_size,
                              hipStream_t stream) {
    const float* x     = (const float*)d_in[0];
    const float* mean_ = (const float*)d_in[1];
    const float* std_  = (const float*)d_in[2];
    float* out = (float*)d_out;

    float* part = (float*)d_ws;   // 4096 f32 (16 chunk roots x 256 images)

    kA1<<<IMG_B * 16, 256, 0, stream>>>(x, mean_, std_, part);

    dim3 gridB(16, 3, IMG_B);
    kB<<<gridB, 256, 0, stream>>>(x, mean_, std_, part, out);
}

// Round 10
// 97.509 us; speedup vs baseline: 5.9105x; 1.2242x over previous
//
#include <hip/hip_runtime.h>

#define IMG_B 256
#define IMG_H 224
#define IMG_W 224
#define HWPIX 50176

// exact IEEE f32 ops, no contraction, matching numpy's elementwise semantics
#define FA(a,b) __fadd_rn((a),(b))
#define FM(a,b) __fmul_rn((a),(b))
#define FS(a,b) __fsub_rn((a),(b))
#define FD(a,b) __fdiv_rn((a),(b))

// python-float scalars cast to f32 exactly as numpy weak-scalar promotion does
__device__ __forceinline__ float VBF()   { return (float)(9.0/30.0*(1.9-0.1)+0.1); }
__device__ __forceinline__ float OMVBF() { return (float)(1.0 - (9.0/30.0*(1.9-0.1)+0.1)); }
__device__ __forceinline__ float VSF()   { return (float)(9.0/30.0*1.0); }

// 6 y-taps (cols j-1..j+4) from LDS row r using ONLY aligned float4 reads
// (neighbor quads supply the edge taps; no stride-16B scalar LDS reads)
__device__ __forceinline__ void lds_y6(const float* __restrict__ r, int j, float* y6) {
    const float4 vC = *(const float4*)(r + j);
    const float4 vL = *(const float4*)(r + (j > 0 ? j - 4 : 0));
    const float4 vR = *(const float4*)(r + (j + 4 < IMG_W ? j + 4 : IMG_W - 4));
    y6[0] = (j > 0) ? vL.w : 0.0f;
    y6[1] = vC.x; y6[2] = vC.y; y6[3] = vC.z; y6[4] = vC.w;
    y6[5] = (j + 4 < IMG_W) ? vR.x : 0.0f;
}

// exact blur fold (9 terms, raster order) + y1 blend, for 4 pixels
__device__ __forceinline__ void y1_from_rows(const float* yU, const float* yC,
                                             const float* yD, float* y1o) {
    const float WN = 1.0f / 13.0f, WC = 5.0f / 13.0f;
#pragma unroll
    for (int mm = 0; mm < 4; ++mm) {
        float acc = 0.0f;
        acc = FA(acc, FM(WN, yU[mm + 0]));
        acc = FA(acc, FM(WN, yU[mm + 1]));
        acc = FA(acc, FM(WN, yU[mm + 2]));
        acc = FA(acc, FM(WN, yC[mm + 0]));
        acc = FA(acc, FM(WC, yC[mm + 1]));
        acc = FA(acc, FM(WN, yC[mm + 2]));
        acc = FA(acc, FM(WN, yD[mm + 0]));
        acc = FA(acc, FM(WN, yD[mm + 1]));
        acc = FA(acc, FM(WN, yD[mm + 2]));
        y1o[mm] = FA(FM(yC[mm + 1], VBF()), FM(acc, OMVBF()));
    }
}

// prefetch raw x float4s for the 896 staged quads (rows r0-1..r0+14) into regs
__device__ __forceinline__ void stage_load(const float* __restrict__ xc, int r0,
                                           int t, float4* pf) {
#pragma unroll
    for (int u = 0; u < 4; ++u) {
        const int idx = t + 256 * u;
        float4 v = make_float4(0.f, 0.f, 0.f, 0.f);
        if (idx < 896) {
            const int row = idx / 56, c4 = (idx % 56) * 4;
            const int gi = r0 - 1 + row;
            if (gi >= 0 && gi < IMG_H)
                v = *(const float4*)(xc + (size_t)gi * IMG_W + c4);
        }
        pf[u] = v;
    }
}

// write y = s*x+m to LDS from prefetched regs; pad rows -> exact 0
__device__ __forceinline__ void stage_write(float s, float m, int r0, int t,
                                            const float4* pf, float* __restrict__ Y) {
#pragma unroll
    for (int u = 0; u < 4; ++u) {
        const int idx = t + 256 * u;
        if (idx < 896) {
            const int row = idx / 56, c4 = (idx % 56) * 4;
            const int gi = r0 - 1 + row;
            float4 w;
            if (gi >= 0 && gi < IMG_H) {
                w.x = FA(FM(pf[u].x, s), m);
                w.y = FA(FM(pf[u].y, s), m);
                w.z = FA(FM(pf[u].z, s), m);
                w.w = FA(FM(pf[u].w, s), m);
            } else {
                w.x = w.y = w.z = w.w = 0.0f;
            }
            *(float4*)(&Y[row * IMG_W + c4]) = w;
        }
    }
}

// ---- Kernel A1: one block = one 3136-px chunk (14 rows) = 32 aligned leaves of
// the numpy pairwise tree. Channel loop: stage y (reg-prefetched), compute y1
// from LDS (all-b128), accumulate gray in REGISTERS. Then one float4 write to
// leaf-padded G2, conflict-free chain walk, exact combine. part[b*16+ck]=root.
__global__ __launch_bounds__(256, 4) void kA1(const float* __restrict__ x,
                                              const float* __restrict__ mean_,
                                              const float* __restrict__ std_,
                                              float* __restrict__ part) {
    const int ck = blockIdx.x & 15, b = blockIdx.x >> 4;
    const int t = threadIdx.x;
    const int r0 = ck * 14;

    __shared__ float Y[16 * IMG_W];   // 14336 B
    __shared__ float G2[32 * 104];    // 13312 B, leaf-padded gray (stride 104)
    __shared__ float CH[256];
    __shared__ float LS[32];

    const float CGRAY[3] = {0.299f, 0.587f, 0.114f};

    float4 pf[4];
    float4 gacc[4];

    stage_load(x + (size_t)(b * 3 + 0) * HWPIX, r0, t, pf);

    for (int c = 0; c < 3; ++c) {
        const float s = std_[c], m = mean_[c];
        stage_write(s, m, r0, t, pf, Y);
        __syncthreads();
        if (c < 2) stage_load(x + (size_t)(b * 3 + c + 1) * HWPIX, r0, t, pf);

        const float cg = CGRAY[c];
#pragma unroll
        for (int u = 0; u < 4; ++u) {
            const int qi = t + 256 * u;
            if (qi < 784) {
                const int lr = qi / 56 + 1, j = (qi % 56) * 4;
                float yU[6], yC[6], yD[6], y1[4];
                lds_y6(&Y[(lr - 1) * IMG_W], j, yU);
                lds_y6(&Y[lr * IMG_W],       j, yC);
                lds_y6(&Y[(lr + 1) * IMG_W], j, yD);
                y1_from_rows(yU, yC, yD, y1);
                float4 ga = gacc[u];
                if (c == 0) {
                    ga.x = FM(cg, y1[0]); ga.y = FM(cg, y1[1]);
                    ga.z = FM(cg, y1[2]); ga.w = FM(cg, y1[3]);
                } else {
                    ga.x = FA(ga.x, FM(cg, y1[0])); ga.y = FA(ga.y, FM(cg, y1[1]));
                    ga.z = FA(ga.z, FM(cg, y1[2])); ga.w = FA(ga.w, FM(cg, y1[3]));
                }
                gacc[u] = ga;
            }
        }
        __syncthreads();   // Y restaged next channel
    }

    // ---- single conflict-free-ish float4 write of gray into leaf-padded G2 ----
#pragma unroll
    for (int u = 0; u < 4; ++u) {
        const int qi = t + 256 * u;
        if (qi < 784) {
            const int pl = qi * 4;
            const int grp = pl / 392;
            const int rem = pl - grp * 392;
            int li = rem / 96; if (li > 3) li = 3;
            const int o = rem - 96 * li;
            *(float4*)(&G2[(grp * 4 + li) * 104 + o]) = gacc[u];
        }
    }
    __syncthreads();

    // ---- 8 chains per leaf (exact numpy base case); banks 2-way only ----
    {
        const int leaf = t >> 3, e = t & 7;
        const int base = leaf * 104 + e;
        const int nk = ((leaf & 3) == 3) ? 13 : 12;
        float r = G2[base];
        for (int k = 1; k < nk; ++k) r = FA(r, G2[base + 8 * k]);
        CH[t] = r;   // t == leaf*8+e
    }
    __syncthreads();

    if (t < 32) {
        const float* c8 = &CH[t * 8];
        LS[t] = FA(FA(FA(c8[0], c8[1]), FA(c8[2], c8[3])),
                   FA(FA(c8[4], c8[5]), FA(c8[6], c8[7])));
    }
    __syncthreads();

    if (t == 0) {
        float v[32];
#pragma unroll
        for (int k = 0; k < 32; ++k) v[k] = LS[k];
        for (int n = 16; n >= 1; n >>= 1)
            for (int k = 0; k < n; ++k) v[k] = FA(v[2 * k], v[2 * k + 1]);
        part[blockIdx.x] = v[0];
    }
}

// ---- Kernel B: one block = one 14-row chunk of one (b,c); staged like kA1 ----
__global__ __launch_bounds__(256) void kB(const float* __restrict__ x,
                                          const float* __restrict__ mean_,
                                          const float* __restrict__ std_,
                                          const float* __restrict__ part,
                                          float* __restrict__ out) {
    const int ck = blockIdx.x, c = blockIdx.y, b = blockIdx.z;
    const int t = threadIdx.x;
    const int r0 = ck * 14;

    __shared__ float Y[16 * IMG_W];
    __shared__ float gsh;

    const float s = std_[c], m = mean_[c];
    float4 pf[4];
    stage_load(x + (size_t)(b * 3 + c) * HWPIX, r0, t, pf);
    stage_write(s, m, r0, t, pf, Y);

    if (t == 0) {
        // exact 4-level fold of the 16 chunk roots, / 50176
        float v[16];
#pragma unroll
        for (int k = 0; k < 16; ++k) v[k] = part[b * 16 + k];
#pragma unroll
        for (int n = 8; n >= 1; n >>= 1)
#pragma unroll
            for (int k = 0; k < 8; ++k)
                if (k < n) v[k] = FA(v[2 * k], v[2 * k + 1]);
        gsh = FD(v[0], 50176.0f);
    }
    __syncthreads();
    const float g = gsh;

    float* oc = out + (size_t)(b * 3 + c) * HWPIX + (size_t)r0 * IMG_W;

    for (int qi = t; qi < 784; qi += 256) {
        const int lr = qi / 56 + 1, j = (qi % 56) * 4;
        float yU[6], yC[6], yD[6], y1[4];
        lds_y6(&Y[(lr - 1) * IMG_W], j, yU);
        lds_y6(&Y[lr * IMG_W],       j, yC);
        lds_y6(&Y[(lr + 1) * IMG_W], j, yD);
        y1_from_rows(yU, yC, yD, y1);

        float ov[4];
#pragma unroll
        for (int mm = 0; mm < 4; ++mm) {
            const float y2 = FA(FM(y1[mm], VBF()), FM(g, OMVBF()));
            const float y3 = FM(y2, VBF());
            const float y4 = (y3 < VSF()) ? y3 : FS(1.0f, y3);
            ov[mm] = FD(FS(y4, m), s);
        }
        float4 o;
        o.x = ov[0]; o.y = ov[1]; o.z = ov[2]; o.w = ov[3];
        *(float4*)(oc + (size_t)(lr - 1) * IMG_W + j) = o;
    }
}

extern "C" void kernel_launch(void* const* d_in, const int* in_sizes, int n_in,
                              void* d_out, int out_size, void* d_ws, size_t ws_size,
                              hipStream_t stream) {
    const float* x     = (const float*)d_in[0];
    const float* mean_ = (const float*)d_in[1];
    const float* std_  = (const float*)d_in[2];
    float* out = (float*)d_out;

    float* part = (float*)d_ws;   // 4096 f32 (16 chunk roots x 256 images)

    kA1<<<IMG_B * 16, 256, 0, stream>>>(x, mean_, std_, part);

    dim3 gridB(16, 3, IMG_B);
    kB<<<gridB, 256, 0, stream>>>(x, mean_, std_, part, out);
}